// Round 2
// baseline (1231.416 us; speedup 1.0000x reference)
//
#include <hip/hip_runtime.h>
#include <hip/hip_bf16.h>
#include <math.h>

// Problem constants
#define BATCH   65536L
#define EDIM    512
#define QKVDIM  1536
#define CONCATD 1024
#define HIDD    512
#define OUTD    256

typedef __bf16 bf16_t;
typedef __bf16 bf16x8 __attribute__((ext_vector_type(8)));
typedef __bf16 bf16x4 __attribute__((ext_vector_type(4)));
typedef float  floatx4 __attribute__((ext_vector_type(4)));

static_assert(sizeof(bf16x8) == 16, "bf16x8 must be 16B");

__device__ __forceinline__ void gload16(const void* g, void* l) {
  __builtin_amdgcn_global_load_lds(
      (__attribute__((address_space(1))) void*)(g),
      (__attribute__((address_space(3))) void*)(l), 16, 0, 0);
}

// ---------- convert inputs: interleave visual/text rows -> token-major bf16 ----------
// grid: ntok*64/256 blocks; one thread per 8 elements
__global__ __launch_bounds__(256) void convert_x_kernel(
    const float* __restrict__ vis, const float* __restrict__ txt,
    bf16_t* __restrict__ dst) {
  long idx = (long)blockIdx.x * 256 + threadIdx.x;
  long t = idx >> 6;            // local token
  int  c = (int)(idx & 63) * 8;
  long b = t >> 1;              // local batch row
  const float* src = ((t & 1) ? txt : vis) + b * EDIM + c;
  float4 f0 = *(const float4*)src;
  float4 f1 = *(const float4*)(src + 4);
  bf16x8 o;
  o[0] = (bf16_t)f0.x; o[1] = (bf16_t)f0.y; o[2] = (bf16_t)f0.z; o[3] = (bf16_t)f0.w;
  o[4] = (bf16_t)f1.x; o[5] = (bf16_t)f1.y; o[6] = (bf16_t)f1.z; o[7] = (bf16_t)f1.w;
  *(bf16x8*)(dst + t * EDIM + c) = o;
}

// ---------- convert all weight matrices fp32 -> bf16 (concatenated regions) ----------
__global__ __launch_bounds__(256) void convert_w_kernel(
    const float* __restrict__ wq, const float* __restrict__ wo,
    const float* __restrict__ w1, const float* __restrict__ w2,
    bf16_t* __restrict__ dst) {
  long idx = ((long)blockIdx.x * 256 + threadIdx.x) * 8;  // 1703936 elems total
  const long n0 = 786432, n1 = n0 + 262144, n2 = n1 + 524288;
  const float* src; long off;
  if (idx < n0)      { src = wq; off = idx; }
  else if (idx < n1) { src = wo; off = idx - n0; }
  else if (idx < n2) { src = w1; off = idx - n1; }
  else               { src = w2; off = idx - n2; }
  float4 f0 = *(const float4*)(src + off);
  float4 f1 = *(const float4*)(src + off + 4);
  bf16x8 o;
  o[0] = (bf16_t)f0.x; o[1] = (bf16_t)f0.y; o[2] = (bf16_t)f0.z; o[3] = (bf16_t)f0.w;
  o[4] = (bf16_t)f1.x; o[5] = (bf16_t)f1.y; o[6] = (bf16_t)f1.z; o[7] = (bf16_t)f1.w;
  *(bf16x8*)(dst + idx) = o;
}

// ---------- m97-style bf16 GEMM: C(MxN) = A(MxK) @ Bt(NxK)^T + bias, epilogue ----------
// EPI: 0 = bias only, 1 = bias + exact gelu
template<int EPI>
__global__ __launch_bounds__(256) void gemm_bt_kernel(
    const bf16_t* __restrict__ A, const bf16_t* __restrict__ Bt,
    const float* __restrict__ bias, bf16_t* __restrict__ C,
    int M, int N, int K, int ntiles) {
  __shared__ __attribute__((aligned(16))) bf16_t sA[128 * 32];
  __shared__ __attribute__((aligned(16))) bf16_t sB[128 * 32];
  const int bid  = blockIdx.x;
  const int mt   = bid / ntiles;
  const int nt   = bid % ntiles;
  const int tid  = threadIdx.x;
  const int wave = tid >> 6;
  const int lane = tid & 63;
  const int wm   = wave >> 1;   // wave row (2x2 wave grid, each 64x64)
  const int wn   = wave & 1;

  floatx4 acc[4][4];
  #pragma unroll
  for (int i = 0; i < 4; i++)
    #pragma unroll
    for (int j = 0; j < 4; j++) acc[i][j] = (floatx4){0.f, 0.f, 0.f, 0.f};

  // staging: rows {0,64}+wave*16+lane/4, cols (lane&3)*8
  const int srow = wave * 16 + (lane >> 2);
  const int scol = (lane & 3) * 8;
  const bf16_t* Ag0 = A  + (long)(mt * 128 + srow) * K + scol;
  const bf16_t* Ag1 = Ag0 + 64L * K;
  const bf16_t* Bg0 = Bt + (long)(nt * 128 + srow) * K + scol;
  const bf16_t* Bg1 = Bg0 + 64L * K;
  // wave-uniform LDS bases: lane l lands at base + l*16B
  bf16_t* sA0 = sA + wave * 512;
  bf16_t* sA1 = sA + 2048 + wave * 512;
  bf16_t* sB0 = sB + wave * 512;
  bf16_t* sB1 = sB + 2048 + wave * 512;

  const int m_l = lane & 15;
  const int kq  = (lane >> 4) * 8;

  for (int k0 = 0; k0 < K; k0 += 32) {
    __syncthreads();          // previous iteration's LDS reads complete
    gload16(Ag0 + k0, sA0);
    gload16(Ag1 + k0, sA1);
    gload16(Bg0 + k0, sB0);
    gload16(Bg1 + k0, sB1);
    __syncthreads();          // staging complete

    bf16x8 a[4], b[4];
    #pragma unroll
    for (int i = 0; i < 4; i++)
      a[i] = *(const bf16x8*)&sA[(wm * 64 + i * 16 + m_l) * 32 + kq];
    #pragma unroll
    for (int j = 0; j < 4; j++)
      b[j] = *(const bf16x8*)&sB[(wn * 64 + j * 16 + m_l) * 32 + kq];
    #pragma unroll
    for (int i = 0; i < 4; i++)
      #pragma unroll
      for (int j = 0; j < 4; j++)
        acc[i][j] = __builtin_amdgcn_mfma_f32_16x16x32_bf16(a[i], b[j], acc[i][j], 0, 0, 0);
  }

  // epilogue: C/D layout col=lane&15, row=(lane>>4)*4+reg  [m89-verified]
  const int col_l = lane & 15;
  const int row_q = (lane >> 4) * 4;
  float bj[4];
  #pragma unroll
  for (int j = 0; j < 4; j++)
    bj[j] = bias[nt * 128 + wn * 64 + j * 16 + col_l];
  #pragma unroll
  for (int i = 0; i < 4; i++) {
    #pragma unroll
    for (int r = 0; r < 4; r++) {
      long row = (long)(mt * 128 + wm * 64 + i * 16 + row_q + r);
      bf16_t* crow = C + row * N + nt * 128 + wn * 64 + col_l;
      #pragma unroll
      for (int j = 0; j < 4; j++) {
        float v = acc[i][j][r] + bj[j];
        if (EPI == 1) v = 0.5f * v * (1.0f + erff(v * 0.70710678118654752f));
        crow[j * 16] = (bf16_t)v;
      }
    }
  }
}

// ---------- attention: per (row, head) 2x2 softmax + ctx; head-mean weights ----------
// grid: nb*8/256 blocks
__global__ __launch_bounds__(256) void attn_kernel(
    const bf16_t* __restrict__ qkv, bf16_t* __restrict__ ctx,
    float* __restrict__ wout) {
  long idx = (long)blockIdx.x * 256 + threadIdx.x;
  long b = idx >> 3;   // local batch row
  int  h = (int)(idx & 7);
  const bf16_t* base = qkv + (b * 2) * QKVDIM + h * 64;
  const bf16_t* q0 = base;
  const bf16_t* q1 = base + QKVDIM;
  const bf16_t* k0 = base + EDIM;
  const bf16_t* k1 = base + EDIM + QKVDIM;
  const bf16_t* v0 = base + 2 * EDIM;
  const bf16_t* v1 = base + 2 * EDIM + QKVDIM;

  float s00 = 0.f, s01 = 0.f, s10 = 0.f, s11 = 0.f;
  #pragma unroll
  for (int c = 0; c < 64; c += 8) {
    bf16x8 a0 = *(const bf16x8*)(q0 + c), a1 = *(const bf16x8*)(q1 + c);
    bf16x8 c0 = *(const bf16x8*)(k0 + c), c1 = *(const bf16x8*)(k1 + c);
    #pragma unroll
    for (int r = 0; r < 8; r++) {
      float x0 = (float)a0[r], x1 = (float)a1[r];
      float y0 = (float)c0[r], y1 = (float)c1[r];
      s00 += x0 * y0; s01 += x0 * y1; s10 += x1 * y0; s11 += x1 * y1;
    }
  }
  const float sc = 0.125f;  // 1/sqrt(64)
  s00 *= sc; s01 *= sc; s10 *= sc; s11 *= sc;
  float m0 = fmaxf(s00, s01), m1 = fmaxf(s10, s11);
  float e00 = __expf(s00 - m0), e01 = __expf(s01 - m0);
  float e10 = __expf(s10 - m1), e11 = __expf(s11 - m1);
  float d0 = e00 + e01, d1 = e10 + e11;
  float a00 = e00 / d0, a01 = e01 / d0, a10 = e10 / d1, a11 = e11 / d1;

  // weights = attn.mean over heads; 8 heads live in 8 adjacent lanes
  float r00 = a00, r01 = a01, r10 = a10, r11 = a11;
  #pragma unroll
  for (int mask = 1; mask < 8; mask <<= 1) {
    r00 += __shfl_xor(r00, mask);
    r01 += __shfl_xor(r01, mask);
    r10 += __shfl_xor(r10, mask);
    r11 += __shfl_xor(r11, mask);
  }
  if (h == 0) {
    float4 wv = make_float4(r00 * 0.125f, r01 * 0.125f, r10 * 0.125f, r11 * 0.125f);
    *(float4*)(wout + b * 4) = wv;
  }

  bf16_t* o0 = ctx + (b * 2) * EDIM + h * 64;
  bf16_t* o1 = o0 + EDIM;
  #pragma unroll
  for (int c = 0; c < 64; c += 8) {
    bf16x8 x0 = *(const bf16x8*)(v0 + c), x1 = *(const bf16x8*)(v1 + c);
    bf16x8 t0, t1;
    #pragma unroll
    for (int r = 0; r < 8; r++) {
      float f0 = (float)x0[r], f1 = (float)x1[r];
      t0[r] = (bf16_t)(a00 * f0 + a01 * f1);
      t1[r] = (bf16_t)(a10 * f0 + a11 * f1);
    }
    *(bf16x8*)(o0 + c) = t0;
    *(bf16x8*)(o1 + c) = t1;
  }
}

// ---------- LayerNorm over OUTD=256: one wave per row ----------
// grid: nb/4 blocks
__global__ __launch_bounds__(256) void ln_kernel(
    const bf16_t* __restrict__ O, const float* __restrict__ gamma,
    const float* __restrict__ beta, float* __restrict__ out) {
  int  tid  = threadIdx.x;
  long row  = (long)blockIdx.x * 4 + (tid >> 6);
  int  lane = tid & 63;
  bf16x4 ov = *(const bf16x4*)(O + row * OUTD + lane * 4);
  float v0 = (float)ov[0], v1 = (float)ov[1], v2 = (float)ov[2], v3 = (float)ov[3];
  float s  = v0 + v1 + v2 + v3;
  float s2 = v0 * v0 + v1 * v1 + v2 * v2 + v3 * v3;
  #pragma unroll
  for (int mask = 1; mask < 64; mask <<= 1) {
    s  += __shfl_xor(s, mask);
    s2 += __shfl_xor(s2, mask);
  }
  float mu  = s * (1.0f / 256.0f);
  float var = s2 * (1.0f / 256.0f) - mu * mu;
  float rs  = rsqrtf(var + 1e-5f);
  float4 g  = *(const float4*)(gamma + lane * 4);
  float4 be = *(const float4*)(beta + lane * 4);
  float4 res;
  res.x = (v0 - mu) * rs * g.x + be.x;
  res.y = (v1 - mu) * rs * g.y + be.y;
  res.z = (v2 - mu) * rs * g.z + be.z;
  res.w = (v3 - mu) * rs * g.w + be.w;
  *(float4*)(out + row * OUTD + lane * 4) = res;
}

extern "C" void kernel_launch(void* const* d_in, const int* in_sizes, int n_in,
                              void* d_out, int out_size, void* d_ws, size_t ws_size,
                              hipStream_t stream) {
  (void)in_sizes; (void)n_in; (void)out_size;
  const float* vis   = (const float*)d_in[0];
  const float* txt   = (const float*)d_in[1];
  const float* w_qkv = (const float*)d_in[2];
  const float* b_qkv = (const float*)d_in[3];
  const float* w_out = (const float*)d_in[4];
  const float* b_out = (const float*)d_in[5];
  const float* w1    = (const float*)d_in[6];
  const float* b1    = (const float*)d_in[7];
  const float* w2    = (const float*)d_in[8];
  const float* b2    = (const float*)d_in[9];
  const float* gamma = (const float*)d_in[10];
  const float* beta  = (const float*)d_in[11];
  float* out_fused   = (float*)d_out;
  float* out_weights = out_fused + BATCH * OUTD;

  char* ws = (char*)d_ws;
  const size_t MB = 1024 * 1024;

  // Batch-chunked pipeline sized to ws_size.
  // Peak footprint = 4MB (bf16 weights) + 8192*Bc bytes:
  //   region1 (2048*Bc): X -> CTX -> H
  //   region2 (6144*Bc): QKV -> ATT -> O
  long Bc = BATCH;
  int  nch = 1;
  while ((size_t)(4 * MB) + (size_t)(8192UL * (unsigned long)Bc) > ws_size && nch < 32) {
    Bc >>= 1; nch <<= 1;
  }

  // bf16 weights, concatenated: wq | wo | w1 | w2
  bf16_t* wq_b = (bf16_t*)ws;
  bf16_t* wo_b = wq_b + 786432;
  bf16_t* w1_b = wq_b + 1048576;
  bf16_t* w2_b = wq_b + 1572864;
  convert_w_kernel<<<832, 256, 0, stream>>>(w_qkv, w_out, w1, w2, wq_b);

  bf16_t* reg1 = (bf16_t*)(ws + 4 * MB);                    // 2048*Bc bytes
  bf16_t* reg2 = (bf16_t*)(ws + 4 * MB + (size_t)2048 * Bc);// 6144*Bc bytes

  const long Tc = 2 * Bc;  // tokens per chunk
  for (int c = 0; c < nch; c++) {
    const float* visc = vis + (long)c * Bc * EDIM;
    const float* txtc = txt + (long)c * Bc * EDIM;
    bf16_t* X   = reg1;   // Tc x 512
    bf16_t* QKV = reg2;   // Tc x 1536
    bf16_t* CTX = reg1;   // Tc x 512   (X dead after QKV gemm)
    bf16_t* ATT = reg2;   // Tc x 512   (QKV dead after attn); == flat Bc x 1024
    bf16_t* H   = reg1;   // Bc x 512   (CTX dead after out_proj... read by mlp1 via ATT)
    bf16_t* O   = reg2;   // Bc x 256   (ATT dead after mlp1)

    convert_x_kernel<<<(int)(Tc / 4), 256, 0, stream>>>(visc, txtc, X);
    // QKV: (Tc x 512) @ (1536 x 512)^T
    gemm_bt_kernel<0><<<(int)(Tc / 128) * 12, 256, 0, stream>>>(
        X, wq_b, b_qkv, QKV, (int)Tc, QKVDIM, EDIM, 12);
    attn_kernel<<<(int)(Bc / 32), 256, 0, stream>>>(
        QKV, CTX, out_weights + (long)c * Bc * 4);
    // out_proj: (Tc x 512) @ (512 x 512)^T
    gemm_bt_kernel<0><<<(int)(Tc / 128) * 4, 256, 0, stream>>>(
        CTX, wo_b, b_out, ATT, (int)Tc, EDIM, EDIM, 4);
    // MLP1 + gelu: (Bc x 1024) @ (512 x 1024)^T
    gemm_bt_kernel<1><<<(int)(Bc / 128) * 4, 256, 0, stream>>>(
        ATT, w1_b, b1, H, (int)Bc, HIDD, CONCATD, 4);
    // MLP2: (Bc x 512) @ (256 x 512)^T
    gemm_bt_kernel<0><<<(int)(Bc / 128) * 2, 256, 0, stream>>>(
        H, w2_b, b2, O, (int)Bc, OUTD, HIDD, 2);
    ln_kernel<<<(int)(Bc / 4), 256, 0, stream>>>(
        O, gamma, beta, out_fused + (long)c * Bc * OUTD);
  }
}

// Round 3
// 1159.291 us; speedup vs baseline: 1.0622x; 1.0622x over previous
//
#include <hip/hip_runtime.h>
#include <hip/hip_bf16.h>
#include <math.h>

// Problem constants
#define BATCH   65536L
#define EDIM    512
#define QKVDIM  1536
#define CONCATD 1024
#define HIDD    512
#define OUTD    256

typedef __bf16 bf16_t;
typedef __bf16 bf16x8 __attribute__((ext_vector_type(8)));
typedef __bf16 bf16x4 __attribute__((ext_vector_type(4)));
typedef float  floatx4 __attribute__((ext_vector_type(4)));

static_assert(sizeof(bf16x8) == 16, "bf16x8 must be 16B");

__device__ __forceinline__ void gload16(const void* g, void* l) {
  __builtin_amdgcn_global_load_lds(
      (__attribute__((address_space(1))) void*)(g),
      (__attribute__((address_space(3))) void*)(l), 16, 0, 0);
}

// ---------- convert inputs: interleave visual/text rows -> token-major bf16 ----------
__global__ __launch_bounds__(256) void convert_x_kernel(
    const float* __restrict__ vis, const float* __restrict__ txt,
    bf16_t* __restrict__ dst) {
  long idx = (long)blockIdx.x * 256 + threadIdx.x;
  long t = idx >> 6;            // local token
  int  c = (int)(idx & 63) * 8;
  long b = t >> 1;              // local batch row
  const float* src = ((t & 1) ? txt : vis) + b * EDIM + c;
  float4 f0 = *(const float4*)src;
  float4 f1 = *(const float4*)(src + 4);
  bf16x8 o;
  o[0] = (bf16_t)f0.x; o[1] = (bf16_t)f0.y; o[2] = (bf16_t)f0.z; o[3] = (bf16_t)f0.w;
  o[4] = (bf16_t)f1.x; o[5] = (bf16_t)f1.y; o[6] = (bf16_t)f1.z; o[7] = (bf16_t)f1.w;
  *(bf16x8*)(dst + t * EDIM + c) = o;
}

// ---------- convert weights fp32 -> bf16: wq (786432) | w2 (131072) ----------
__global__ __launch_bounds__(256) void convert_w_kernel(
    const float* __restrict__ wq, const float* __restrict__ w2,
    bf16_t* __restrict__ dst) {
  long idx = ((long)blockIdx.x * 256 + threadIdx.x) * 8;  // 917504 elems total
  const long n0 = 786432;
  const float* src; long off;
  if (idx < n0) { src = wq; off = idx; }
  else          { src = w2; off = idx - n0; }
  float4 f0 = *(const float4*)(src + off);
  float4 f1 = *(const float4*)(src + off + 4);
  bf16x8 o;
  o[0] = (bf16_t)f0.x; o[1] = (bf16_t)f0.y; o[2] = (bf16_t)f0.z; o[3] = (bf16_t)f0.w;
  o[4] = (bf16_t)f1.x; o[5] = (bf16_t)f1.y; o[6] = (bf16_t)f1.z; o[7] = (bf16_t)f1.w;
  *(bf16x8*)(dst + idx) = o;
}

// ---------- fold out_proj into mlp1: Wc[n, e] (512 x 1024) bf16 ----------
// Wc[n, e<512]    = sum_f W1[n, f]       * Wo[f, e]
// Wc[n, 512 + e]  = sum_f W1[n, 512 + f] * Wo[f, e]
// grid: 512 blocks (one per n), 256 threads, 4 outputs each
__global__ __launch_bounds__(256) void wc_kernel(
    const float* __restrict__ w1, const float* __restrict__ wo,
    bf16_t* __restrict__ wc) {
  int n = blockIdx.x;
  int t = threadIdx.x;
  const float* w1v = w1 + (long)n * 1024;
  const float* w1t = w1v + 512;
  float a0 = 0.f, a1 = 0.f, a2 = 0.f, a3 = 0.f;
  for (int f = 0; f < 512; f++) {
    float wv = w1v[f], wt = w1t[f];
    float x0 = wo[f * 512 + t], x1 = wo[f * 512 + t + 256];
    a0 += wv * x0; a1 += wv * x1;
    a2 += wt * x0; a3 += wt * x1;
  }
  bf16_t* out = wc + (long)n * 1024;
  out[t]        = (bf16_t)a0;
  out[t + 256]  = (bf16_t)a1;
  out[t + 512]  = (bf16_t)a2;
  out[t + 768]  = (bf16_t)a3;
}

// ---------- folded bias: bc[n] = b1[n] + sum_f (W1[n,f]+W1[n,512+f]) * bo[f] ----------
__global__ __launch_bounds__(256) void bc_kernel(
    const float* __restrict__ w1, const float* __restrict__ bo,
    const float* __restrict__ b1, float* __restrict__ bc) {
  int n = blockIdx.x * 256 + threadIdx.x;   // grid 2 x 256
  const float* w1row = w1 + (long)n * 1024;
  float acc = b1[n];
  for (int f = 0; f < 512; f++)
    acc += (w1row[f] + w1row[512 + f]) * bo[f];
  bc[n] = acc;
}

// ---------- m97-style bf16 GEMM + LDS xor-swizzle: C = A @ Bt^T + bias ----------
// EPI: 0 = bias only, 1 = bias + exact gelu
// LDS layout: physical chunk slot q_p at row r holds logical k-chunk q_p ^ ((r>>1)&3)
template<int EPI>
__global__ __launch_bounds__(256) void gemm_bt_kernel(
    const bf16_t* __restrict__ A, const bf16_t* __restrict__ Bt,
    const float* __restrict__ bias, bf16_t* __restrict__ C,
    int M, int N, int K, int ntiles) {
  __shared__ __attribute__((aligned(16))) bf16_t sA[128 * 32];
  __shared__ __attribute__((aligned(16))) bf16_t sB[128 * 32];
  const int bid  = blockIdx.x;
  const int mt   = bid / ntiles;
  const int nt   = bid % ntiles;
  const int tid  = threadIdx.x;
  const int wave = tid >> 6;
  const int lane = tid & 63;
  const int wm   = wave >> 1;   // 2x2 wave grid, each 64x64
  const int wn   = wave & 1;

  floatx4 acc[4][4];
  #pragma unroll
  for (int i = 0; i < 4; i++)
    #pragma unroll
    for (int j = 0; j < 4; j++) acc[i][j] = (floatx4){0.f, 0.f, 0.f, 0.f};

  // staging: lane l -> LDS base + l*16B = physical (row srow, chunk lane&3).
  // load the LOGICAL chunk that belongs in that slot: (lane&3) ^ ((srow>>1)&3)
  //   srow = wave*16 + (lane>>2)  =>  (srow>>1)&3 == (lane>>3)&3
  const int srow = wave * 16 + (lane >> 2);
  const int scol = (((lane & 3) ^ ((lane >> 3) & 3)) * 8);
  const bf16_t* Ag0 = A  + (long)(mt * 128 + srow) * K + scol;
  const bf16_t* Ag1 = Ag0 + 64L * K;
  const bf16_t* Bg0 = Bt + (long)(nt * 128 + srow) * K + scol;
  const bf16_t* Bg1 = Bg0 + 64L * K;
  bf16_t* sA0 = sA + wave * 512;
  bf16_t* sA1 = sA + 2048 + wave * 512;
  bf16_t* sB0 = sB + wave * 512;
  bf16_t* sB1 = sB + 2048 + wave * 512;

  const int m_l = lane & 15;
  // read side: logical chunk lane>>4 at row r -> physical (lane>>4) ^ ((r>>1)&3);
  // (r>>1)&3 == (m_l>>1)&3 for all i (row = wm*64 + i*16 + m_l)
  const int kq = (((lane >> 4) ^ ((m_l >> 1) & 3)) * 8);

  for (int k0 = 0; k0 < K; k0 += 32) {
    __syncthreads();          // previous iteration's LDS reads complete
    gload16(Ag0 + k0, sA0);
    gload16(Ag1 + k0, sA1);
    gload16(Bg0 + k0, sB0);
    gload16(Bg1 + k0, sB1);
    __syncthreads();          // staging complete

    bf16x8 a[4], b[4];
    #pragma unroll
    for (int i = 0; i < 4; i++)
      a[i] = *(const bf16x8*)&sA[(wm * 64 + i * 16 + m_l) * 32 + kq];
    #pragma unroll
    for (int j = 0; j < 4; j++)
      b[j] = *(const bf16x8*)&sB[(wn * 64 + j * 16 + m_l) * 32 + kq];
    #pragma unroll
    for (int i = 0; i < 4; i++)
      #pragma unroll
      for (int j = 0; j < 4; j++)
        acc[i][j] = __builtin_amdgcn_mfma_f32_16x16x32_bf16(a[i], b[j], acc[i][j], 0, 0, 0);
  }

  // epilogue: C/D layout col=lane&15, row=(lane>>4)*4+reg  [m89-verified]
  const int col_l = lane & 15;
  const int row_q = (lane >> 4) * 4;
  float bj[4];
  #pragma unroll
  for (int j = 0; j < 4; j++)
    bj[j] = bias[nt * 128 + wn * 64 + j * 16 + col_l];
  #pragma unroll
  for (int i = 0; i < 4; i++) {
    #pragma unroll
    for (int r = 0; r < 4; r++) {
      long row = (long)(mt * 128 + wm * 64 + i * 16 + row_q + r);
      bf16_t* crow = C + row * N + nt * 128 + wn * 64 + col_l;
      #pragma unroll
      for (int j = 0; j < 4; j++) {
        float v = acc[i][j][r] + bj[j];
        if (EPI == 1) v = 0.5f * v * (1.0f + erff(v * 0.70710678118654752f));
        crow[j * 16] = (bf16_t)v;
      }
    }
  }
}

// ---------- attention: per (row, head) 2x2 softmax + ctx; head-mean weights ----------
__global__ __launch_bounds__(256) void attn_kernel(
    const bf16_t* __restrict__ qkv, bf16_t* __restrict__ ctx,
    float* __restrict__ wout) {
  long idx = (long)blockIdx.x * 256 + threadIdx.x;
  long b = idx >> 3;   // local batch row
  int  h = (int)(idx & 7);
  const bf16_t* base = qkv + (b * 2) * QKVDIM + h * 64;
  const bf16_t* q0 = base;
  const bf16_t* q1 = base + QKVDIM;
  const bf16_t* k0 = base + EDIM;
  const bf16_t* k1 = base + EDIM + QKVDIM;
  const bf16_t* v0 = base + 2 * EDIM;
  const bf16_t* v1 = base + 2 * EDIM + QKVDIM;

  float s00 = 0.f, s01 = 0.f, s10 = 0.f, s11 = 0.f;
  #pragma unroll
  for (int c = 0; c < 64; c += 8) {
    bf16x8 a0 = *(const bf16x8*)(q0 + c), a1 = *(const bf16x8*)(q1 + c);
    bf16x8 c0 = *(const bf16x8*)(k0 + c), c1 = *(const bf16x8*)(k1 + c);
    #pragma unroll
    for (int r = 0; r < 8; r++) {
      float x0 = (float)a0[r], x1 = (float)a1[r];
      float y0 = (float)c0[r], y1 = (float)c1[r];
      s00 += x0 * y0; s01 += x0 * y1; s10 += x1 * y0; s11 += x1 * y1;
    }
  }
  const float sc = 0.125f;  // 1/sqrt(64)
  s00 *= sc; s01 *= sc; s10 *= sc; s11 *= sc;
  float m0 = fmaxf(s00, s01), m1 = fmaxf(s10, s11);
  float e00 = __expf(s00 - m0), e01 = __expf(s01 - m0);
  float e10 = __expf(s10 - m1), e11 = __expf(s11 - m1);
  float d0 = e00 + e01, d1 = e10 + e11;
  float a00 = e00 / d0, a01 = e01 / d0, a10 = e10 / d1, a11 = e11 / d1;

  // weights = attn.mean over heads; 8 heads live in 8 adjacent lanes
  float r00 = a00, r01 = a01, r10 = a10, r11 = a11;
  #pragma unroll
  for (int mask = 1; mask < 8; mask <<= 1) {
    r00 += __shfl_xor(r00, mask);
    r01 += __shfl_xor(r01, mask);
    r10 += __shfl_xor(r10, mask);
    r11 += __shfl_xor(r11, mask);
  }
  if (h == 0) {
    float4 wv = make_float4(r00 * 0.125f, r01 * 0.125f, r10 * 0.125f, r11 * 0.125f);
    *(float4*)(wout + b * 4) = wv;
  }

  bf16_t* o0 = ctx + (b * 2) * EDIM + h * 64;
  bf16_t* o1 = o0 + EDIM;
  #pragma unroll
  for (int c = 0; c < 64; c += 8) {
    bf16x8 x0 = *(const bf16x8*)(v0 + c), x1 = *(const bf16x8*)(v1 + c);
    bf16x8 t0, t1;
    #pragma unroll
    for (int r = 0; r < 8; r++) {
      float f0 = (float)x0[r], f1 = (float)x1[r];
      t0[r] = (bf16_t)(a00 * f0 + a01 * f1);
      t1[r] = (bf16_t)(a10 * f0 + a11 * f1);
    }
    *(bf16x8*)(o0 + c) = t0;
    *(bf16x8*)(o1 + c) = t1;
  }
}

// ---------- LayerNorm over OUTD=256: one wave per row ----------
__global__ __launch_bounds__(256) void ln_kernel(
    const bf16_t* __restrict__ O, const float* __restrict__ gamma,
    const float* __restrict__ beta, float* __restrict__ out) {
  int  tid  = threadIdx.x;
  long row  = (long)blockIdx.x * 4 + (tid >> 6);
  int  lane = tid & 63;
  bf16x4 ov = *(const bf16x4*)(O + row * OUTD + lane * 4);
  float v0 = (float)ov[0], v1 = (float)ov[1], v2 = (float)ov[2], v3 = (float)ov[3];
  float s  = v0 + v1 + v2 + v3;
  float s2 = v0 * v0 + v1 * v1 + v2 * v2 + v3 * v3;
  #pragma unroll
  for (int mask = 1; mask < 64; mask <<= 1) {
    s  += __shfl_xor(s, mask);
    s2 += __shfl_xor(s2, mask);
  }
  float mu  = s * (1.0f / 256.0f);
  float var = s2 * (1.0f / 256.0f) - mu * mu;
  float rs  = rsqrtf(var + 1e-5f);
  float4 g  = *(const float4*)(gamma + lane * 4);
  float4 be = *(const float4*)(beta + lane * 4);
  float4 res;
  res.x = (v0 - mu) * rs * g.x + be.x;
  res.y = (v1 - mu) * rs * g.y + be.y;
  res.z = (v2 - mu) * rs * g.z + be.z;
  res.w = (v3 - mu) * rs * g.w + be.w;
  *(float4*)(out + row * OUTD + lane * 4) = res;
}

extern "C" void kernel_launch(void* const* d_in, const int* in_sizes, int n_in,
                              void* d_out, int out_size, void* d_ws, size_t ws_size,
                              hipStream_t stream) {
  (void)in_sizes; (void)n_in; (void)out_size;
  const float* vis   = (const float*)d_in[0];
  const float* txt   = (const float*)d_in[1];
  const float* w_qkv = (const float*)d_in[2];
  const float* b_qkv = (const float*)d_in[3];
  const float* w_out = (const float*)d_in[4];
  const float* b_out = (const float*)d_in[5];
  const float* w1    = (const float*)d_in[6];
  const float* b1    = (const float*)d_in[7];
  const float* w2    = (const float*)d_in[8];
  const float* b2    = (const float*)d_in[9];
  const float* gamma = (const float*)d_in[10];
  const float* beta  = (const float*)d_in[11];
  float* out_fused   = (float*)d_out;
  float* out_weights = out_fused + BATCH * OUTD;

  char* ws = (char*)d_ws;
  const size_t MB = 1024 * 1024;

  // chunked pipeline: footprint = 4MB weights + 8192*Bc bytes
  //   region1 (2048*Bc): X -> CTX -> O
  //   region2 (6144*Bc): QKV -> H
  long Bc = BATCH;
  int  nch = 1;
  while ((size_t)(4 * MB) + (size_t)(8192UL * (unsigned long)Bc) > ws_size && nch < 32) {
    Bc >>= 1; nch <<= 1;
  }

  // bf16 weights: wq (786432) | w2 (131072) | wc (524288) ; bc fp32 at +3MB
  bf16_t* wq_b = (bf16_t*)ws;
  bf16_t* w2_b = wq_b + 786432;
  bf16_t* wc_b = wq_b + 917504;
  float*  bc   = (float*)(ws + 3 * MB);
  convert_w_kernel<<<448, 256, 0, stream>>>(w_qkv, w2, wq_b);
  wc_kernel<<<512, 256, 0, stream>>>(w1, w_out, wc_b);
  bc_kernel<<<2, 256, 0, stream>>>(w1, b_out, b1, bc);

  bf16_t* reg1 = (bf16_t*)(ws + 4 * MB);                     // 2048*Bc bytes
  bf16_t* reg2 = (bf16_t*)(ws + 4 * MB + (size_t)2048 * Bc); // 6144*Bc bytes

  const long Tc = 2 * Bc;  // tokens per chunk
  for (int c = 0; c < nch; c++) {
    const float* visc = vis + (long)c * Bc * EDIM;
    const float* txtc = txt + (long)c * Bc * EDIM;
    bf16_t* X   = reg1;   // Tc x 512
    bf16_t* QKV = reg2;   // Tc x 1536
    bf16_t* CTX = reg1;   // Tc x 512 (X dead after QKV gemm); == flat Bc x 1024
    bf16_t* H   = reg2;   // Bc x 512 (QKV dead after attn)
    bf16_t* O   = reg1;   // Bc x 256 (CTX dead after mlp1)

    convert_x_kernel<<<(int)(Tc / 4), 256, 0, stream>>>(visc, txtc, X);
    // QKV: (Tc x 512) @ (1536 x 512)^T
    gemm_bt_kernel<0><<<(int)(Tc / 128) * 12, 256, 0, stream>>>(
        X, wq_b, b_qkv, QKV, (int)Tc, QKVDIM, EDIM, 12);
    attn_kernel<<<(int)(Bc / 32), 256, 0, stream>>>(
        QKV, CTX, out_weights + (long)c * Bc * 4);
    // MLP1' (out_proj folded) + gelu: (Bc x 1024) @ (512 x 1024)^T
    gemm_bt_kernel<1><<<(int)(Bc / 128) * 4, 256, 0, stream>>>(
        CTX, wc_b, bc, H, (int)Bc, HIDD, CONCATD, 4);
    // MLP2: (Bc x 512) @ (256 x 512)^T
    gemm_bt_kernel<0><<<(int)(Bc / 128) * 2, 256, 0, stream>>>(
        H, w2_b, b2, O, (int)Bc, OUTD, HIDD, 2);
    ln_kernel<<<(int)(Bc / 4), 256, 0, stream>>>(
        O, gamma, beta, out_fused + (long)c * Bc * OUTD);
  }
}